// Round 6
// baseline (140.106 us; speedup 1.0000x reference)
//
#include <hip/hip_runtime.h>

// PeerNet: out = relu-MLP with per-feature kNN-mean (k=6, 1D) in the middle.
// B=4096, D=1024, H1=128, H2=64, O=2. All fp32.

#define NB   4096
#define DIN  1024
#define NH1  128
#define NH2  64
#define SPLITK 4          // gemm1 K split: grid 128x4 = 512 blocks = 2/CU

typedef unsigned long long u64;

// ---------------------------------------------------------------------------
// GEMM1 (split-K): part[s][n][m] = x[m][k in chunk s] @ W1[n][k]^T
// BM=32, BN=128, BK=32, 256 threads, thread tile 4x4. 16 barriers total.
// ---------------------------------------------------------------------------
__global__ __launch_bounds__(256) void gemm1_kernel(const float* __restrict__ A,
                                                    const float* __restrict__ Bw,
                                                    float* __restrict__ CP)
{
    const int K = DIN;
    const int M = NB;
    __shared__ float As[32 * 36];    // [k][m] pad 36 (16B-aligned rows)
    __shared__ float Bs[32 * 132];   // [k][n]
    __shared__ float Cs[32 * 132];   // epilogue bounce
    const int tid = threadIdx.x;
    const int m0  = blockIdx.x * 32;
    const int kb0 = blockIdx.y * (DIN / SPLITK);
    const int tr  = tid >> 5;        // 0..7  -> rows 4*tr..4*tr+3
    const int tc  = tid & 31;        // 0..31 -> cols 4*tc..4*tc+3
    const int am  = tid >> 5, ak = tid & 31;          // A staging
    const int bn  = tid >> 1, bko = (tid & 1) * 16;   // B staging

    float acc[4][4];
#pragma unroll
    for (int i = 0; i < 4; ++i)
#pragma unroll
        for (int j = 0; j < 4; ++j) acc[i][j] = 0.f;

    for (int k0 = 0; k0 < DIN / SPLITK; k0 += 32) {
        const int kb = kb0 + k0;
#pragma unroll
        for (int s = 0; s < 4; ++s)
            As[ak * 36 + am + 8 * s] = A[(size_t)(m0 + am + 8 * s) * K + kb + ak];
#pragma unroll
        for (int i4 = 0; i4 < 4; ++i4) {
            const float4 w = *(const float4*)&Bw[(size_t)bn * K + kb + bko + i4 * 4];
            Bs[(bko + i4 * 4 + 0) * 132 + bn] = w.x;
            Bs[(bko + i4 * 4 + 1) * 132 + bn] = w.y;
            Bs[(bko + i4 * 4 + 2) * 132 + bn] = w.z;
            Bs[(bko + i4 * 4 + 3) * 132 + bn] = w.w;
        }
        __syncthreads();
#pragma unroll
        for (int k = 0; k < 32; ++k) {
            const float4 a = *(const float4*)&As[k * 36 + 4 * tr];
            const float4 b = *(const float4*)&Bs[k * 132 + 4 * tc];
            const float av[4] = {a.x, a.y, a.z, a.w};
#pragma unroll
            for (int mi = 0; mi < 4; ++mi) {
                acc[mi][0] = fmaf(av[mi], b.x, acc[mi][0]);
                acc[mi][1] = fmaf(av[mi], b.y, acc[mi][1]);
                acc[mi][2] = fmaf(av[mi], b.z, acc[mi][2]);
                acc[mi][3] = fmaf(av[mi], b.w, acc[mi][3]);
            }
        }
        __syncthreads();
    }

#pragma unroll
    for (int mi = 0; mi < 4; ++mi)
#pragma unroll
        for (int j = 0; j < 4; ++j)
            Cs[(4 * tr + mi) * 132 + 4 * tc + j] = acc[mi][j];
    __syncthreads();
#pragma unroll
    for (int it = 0; it < 16; ++it) {
        const int idx = it * 256 + tid;
        const int n = idx >> 5, m = idx & 31;
        CP[((size_t)blockIdx.y * NH1 + n) * M + m0 + m] = Cs[m * 132 + n];
    }
}

// ---------------------------------------------------------------------------
// Fused kNN: one block per column (128 blocks, 1024 threads).
// Phase 1: waves 0-7 sort half0 (elems 0..2047), waves 8-15 sort half1 —
//   identical stage counts, so shared __syncthreads() barriers are legal.
//   Load fuses split-K reduce + bias + relu. Key = (fp32 bits << 32) | idx
//   (post-relu >= 0 so fp32 bits order as unsigned; idx -> unique keys,
//   exactly stable sort). j<=32 CE stages via __shfl_xor, j>=64 via LDS.
// Phase 2: rank-merge both halves via binary search (unique keys -> exact
//   permutation) into vs[rank]; each element's rank falls out of the merge.
// Phase 3: greedy 6-window mean from own rank, scatter via res[], coalesced
//   column write.
// ---------------------------------------------------------------------------
__global__ __launch_bounds__(1024) void knn_fused_kernel(const float* __restrict__ P,
                                                         const float* __restrict__ bias,
                                                         float* __restrict__ prtT)
{
    __shared__ u64   sk[NB];     // 32 KB: two independently-sorted halves
    __shared__ float vs[NB];     // 16 KB: merged values by rank
    __shared__ float res[NB];    // 16 KB: results by original index
    const int t    = threadIdx.x;
    const int col  = blockIdx.x;
    const int half = t >> 9;                   // waves 0-7 -> 0, 8-15 -> 1
    const int th   = t & 511;
    const int base = half * 2048;
    const float bv = bias[col];
    const size_t coff = (size_t)col * NB + base;

    u64 v[4];
#pragma unroll
    for (int q = 0; q < 4; ++q) {
        const int i = th + q * 512;
        float a = P[coff + i]
                + P[(size_t)NH1 * NB + coff + i]
                + P[(size_t)2 * NH1 * NB + coff + i]
                + P[(size_t)3 * NH1 * NB + coff + i] + bv;
        a = fmaxf(a, 0.f);
        v[q] = ((u64)__float_as_uint(a) << 32) | (unsigned)(base + i);
    }

    // k = 2..64 entirely in registers (0 barriers)
#pragma unroll
    for (int k = 2; k <= 64; k <<= 1) {
#pragma unroll
        for (int j = k >> 1; j > 0; j >>= 1) {
#pragma unroll
            for (int q = 0; q < 4; ++q) {
                const int i = q * 512 + th;
                const u64 p = __shfl_xor(v[q], j);
                const bool up  = ((i & k) == 0);
                const bool low = ((i & j) == 0);
                const u64 mn = (v[q] < p) ? v[q] : p;
                const u64 mx = (v[q] < p) ? p : v[q];
                v[q] = (low == up) ? mn : mx;
            }
        }
    }
#pragma unroll
    for (int q = 0; q < 4; ++q) sk[base + th + q * 512] = v[q];
    __syncthreads();

    for (int k = 128; k <= 2048; k <<= 1) {
        for (int j = k >> 1; j >= 64; j >>= 1) {
#pragma unroll
            for (int p = 0; p < 2; ++p) {
                const int c = th + p * 512;
                const int i = ((c & ~(j - 1)) << 1) | (c & (j - 1));
                const int ixj = i | j;
                const u64 a = sk[base + i], b = sk[base + ixj];
                const bool up = ((i & k) == 0);
                if ((a > b) == up) { sk[base + i] = b; sk[base + ixj] = a; }
            }
            __syncthreads();
        }
        // j = 32..1 in registers
#pragma unroll
        for (int q = 0; q < 4; ++q) v[q] = sk[base + th + q * 512];
#pragma unroll
        for (int j = 32; j > 0; j >>= 1) {
#pragma unroll
            for (int q = 0; q < 4; ++q) {
                const int i = q * 512 + th;
                const u64 p = __shfl_xor(v[q], j);
                const bool up  = ((i & k) == 0);
                const bool low = ((i & j) == 0);
                const u64 mn = (v[q] < p) ? v[q] : p;
                const u64 mx = (v[q] < p) ? p : v[q];
                v[q] = (low == up) ? mn : mx;
            }
        }
#pragma unroll
        for (int q = 0; q < 4; ++q) sk[base + th + q * 512] = v[q];
        __syncthreads();
    }

    // Phase 2: rank-merge. Each thread ranks 2 half0 elems + 2 half1 elems.
    int   myrank[4];
    float myval[4];
    int   myidx[4];
#pragma unroll
    for (int p = 0; p < 2; ++p) {
        const int j = t + p * 1024;             // 0..2047
        {   // half0 sorted elem j: rank = j + #(half1 keys < key)
            const u64 key = sk[j];
            int lo = 0, hi = 2048;
            while (lo < hi) { const int mid = (lo + hi) >> 1; if (sk[2048 + mid] < key) lo = mid + 1; else hi = mid; }
            const int rank  = j + lo;
            const float val = __uint_as_float((unsigned)(key >> 32));
            vs[rank] = val;
            myrank[p] = rank; myval[p] = val; myidx[p] = (int)(key & 0xffffffffu);
        }
        {   // half1 sorted elem j: rank = j + #(half0 keys < key)
            const u64 key = sk[2048 + j];
            int lo = 0, hi = 2048;
            while (lo < hi) { const int mid = (lo + hi) >> 1; if (sk[mid] < key) lo = mid + 1; else hi = mid; }
            const int rank  = j + lo;
            const float val = __uint_as_float((unsigned)(key >> 32));
            vs[rank] = val;
            myrank[2 + p] = rank; myval[2 + p] = val; myidx[2 + p] = (int)(key & 0xffffffffu);
        }
    }
    __syncthreads();

    // Phase 3: greedy 6-window from own rank
#pragma unroll
    for (int p = 0; p < 4; ++p) {
        const float v0 = myval[p];
        int l = myrank[p], h = myrank[p];
        float sum = v0;  // self
#pragma unroll
        for (int it = 0; it < 5; ++it) {
            const int li = (l > 0) ? l - 1 : 0;
            const int ri = (h < NB - 1) ? h + 1 : NB - 1;
            const float sl = vs[li];
            const float sr = vs[ri];
            const float dl = (l > 0) ? (v0 - sl) : 1e30f;
            const float dr = (h < NB - 1) ? (sr - v0) : 1e30f;
            if (dl <= dr) { sum += sl; l = li; }
            else          { sum += sr; h = ri; }
        }
        res[myidx[p]] = sum * (1.0f / 6.0f);
    }
    __syncthreads();

    float* __restrict__ dst = prtT + (size_t)col * NB;
#pragma unroll
    for (int p = 0; p < 4; ++p) dst[t + p * 1024] = res[t + p * 1024];
}

// ---------------------------------------------------------------------------
// Fused tail: out = (relu(relu(prT^T @ Wpr^T + bpr) @ W2^T + b2)) @ Wo^T + bo
// Grid 256 blocks x 16 rows, 256 threads.
// ---------------------------------------------------------------------------
__global__ __launch_bounds__(256) void tail_kernel(const float* __restrict__ AT,
                                                   const float* __restrict__ Wpr,
                                                   const float* __restrict__ bpr,
                                                   const float* __restrict__ W2,
                                                   const float* __restrict__ b2,
                                                   const float* __restrict__ Wo,
                                                   const float* __restrict__ bo,
                                                   float* __restrict__ out)
{
    __shared__ float As[NH1 * 17];
    __shared__ float Bs[32 * 132];
    __shared__ float Ps[16 * 132];
    __shared__ float Rs[16 * 32];
    const int tid = threadIdx.x;
    const int m0  = blockIdx.x * 16;

    {
        const int row = tid >> 2;
        const int f   = (tid & 3) * 4;
#pragma unroll
        for (int h = 0; h < 2; ++h) {
            const int k = row + h * 64;
            const float4 v = *(const float4*)&AT[(size_t)k * NB + m0 + f];
            As[k * 17 + f + 0] = v.x;
            As[k * 17 + f + 1] = v.y;
            As[k * 17 + f + 2] = v.z;
            As[k * 17 + f + 3] = v.w;
        }
    }

    const int m  = tid & 15;
    const int g  = tid >> 4;     // 0..15
    const int n0 = g * 8;

    float acc[8];
#pragma unroll
    for (int j = 0; j < 8; ++j) acc[j] = 0.f;

    for (int k0 = 0; k0 < NH1; k0 += 32) {
        {
            const int n  = tid >> 1;
            const int ko = (tid & 1) * 16;
#pragma unroll
            for (int i4 = 0; i4 < 4; ++i4) {
                const float4 v = *(const float4*)&Wpr[(size_t)n * NH1 + k0 + ko + i4 * 4];
                Bs[(ko + i4 * 4 + 0) * 132 + n] = v.x;
                Bs[(ko + i4 * 4 + 1) * 132 + n] = v.y;
                Bs[(ko + i4 * 4 + 2) * 132 + n] = v.z;
                Bs[(ko + i4 * 4 + 3) * 132 + n] = v.w;
            }
        }
        __syncthreads();
#pragma unroll
        for (int kk = 0; kk < 32; ++kk) {
            const float a   = As[(k0 + kk) * 17 + m];
            const float4 b0 = *(const float4*)&Bs[kk * 132 + n0];
            const float4 b1 = *(const float4*)&Bs[kk * 132 + n0 + 4];
            acc[0] = fmaf(a, b0.x, acc[0]);
            acc[1] = fmaf(a, b0.y, acc[1]);
            acc[2] = fmaf(a, b0.z, acc[2]);
            acc[3] = fmaf(a, b0.w, acc[3]);
            acc[4] = fmaf(a, b1.x, acc[4]);
            acc[5] = fmaf(a, b1.y, acc[5]);
            acc[6] = fmaf(a, b1.z, acc[6]);
            acc[7] = fmaf(a, b1.w, acc[7]);
        }
        __syncthreads();
    }
#pragma unroll
    for (int j = 0; j < 8; ++j)
        Ps[m * 132 + n0 + j] = fmaxf(acc[j] + bpr[n0 + j], 0.f);
    __syncthreads();

    const int j0 = g * 4;
    float acc2[4] = {0.f, 0.f, 0.f, 0.f};
    for (int n0c = 0; n0c < NH1; n0c += 32) {
        {
            const int j2 = tid >> 2;
            const int no = (tid & 3) * 8;
#pragma unroll
            for (int i4 = 0; i4 < 2; ++i4) {
                const float4 v = *(const float4*)&W2[(size_t)j2 * NH1 + n0c + no + i4 * 4];
                Bs[(no + i4 * 4 + 0) * 68 + j2] = v.x;
                Bs[(no + i4 * 4 + 1) * 68 + j2] = v.y;
                Bs[(no + i4 * 4 + 2) * 68 + j2] = v.z;
                Bs[(no + i4 * 4 + 3) * 68 + j2] = v.w;
            }
        }
        __syncthreads();
#pragma unroll
        for (int nn = 0; nn < 32; ++nn) {
            const float p  = Ps[m * 132 + n0c + nn];
            const float4 w = *(const float4*)&Bs[nn * 68 + j0];
            acc2[0] = fmaf(p, w.x, acc2[0]);
            acc2[1] = fmaf(p, w.y, acc2[1]);
            acc2[2] = fmaf(p, w.z, acc2[2]);
            acc2[3] = fmaf(p, w.w, acc2[3]);
        }
        __syncthreads();
    }

    float po0 = 0.f, po1 = 0.f;
#pragma unroll
    for (int j = 0; j < 4; ++j) {
        const float h = fmaxf(acc2[j] + b2[j0 + j], 0.f);
        po0 = fmaf(h, Wo[j0 + j], po0);
        po1 = fmaf(h, Wo[NH2 + j0 + j], po1);
    }
    Rs[g * 32 + m * 2 + 0] = po0;
    Rs[g * 32 + m * 2 + 1] = po1;
    __syncthreads();
    if (tid < 32) {
        const int mm = tid >> 1, o = tid & 1;
        float sum = 0.f;
#pragma unroll
        for (int gg = 0; gg < 16; ++gg) sum += Rs[gg * 32 + mm * 2 + o];
        out[(size_t)(m0 + mm) * 2 + o] = sum + bo[o];
    }
}

extern "C" void kernel_launch(void* const* d_in, const int* in_sizes, int n_in,
                              void* d_out, int out_size, void* d_ws, size_t ws_size,
                              hipStream_t stream)
{
    const float* x   = (const float*)d_in[0];
    const float* W1  = (const float*)d_in[1];
    const float* b1  = (const float*)d_in[2];
    const float* Wpr = (const float*)d_in[3];
    const float* bpr = (const float*)d_in[4];
    const float* W2  = (const float*)d_in[5];
    const float* b2  = (const float*)d_in[6];
    const float* Wo  = (const float*)d_in[7];
    const float* bo  = (const float*)d_in[8];

    float* ws   = (float*)d_ws;
    float* part = ws;                               // [4][128][4096]  8 MB
    float* prtT = ws + SPLITK * NH1 * NB;           // [128][4096]     2 MB

    gemm1_kernel<<<dim3(NB / 32, SPLITK), 256, 0, stream>>>(x, W1, part);
    knn_fused_kernel<<<dim3(NH1), 1024, 0, stream>>>(part, b1, prtT);
    tail_kernel<<<dim3(NB / 16), 256, 0, stream>>>(prtT, Wpr, bpr, W2, b2, Wo, bo,
                                                   (float*)d_out);
}

// Round 7
// 132.959 us; speedup vs baseline: 1.0538x; 1.0538x over previous
//
#include <hip/hip_runtime.h>

// PeerNet: out = relu-MLP with per-feature kNN-mean (k=6, 1D) in the middle.
// B=4096, D=1024, H1=128, H2=64, O=2. All fp32.
// R7 = exact revert to the R4 configuration (best measured: 132.9 us).
// R5 (u64 kv-sort, fused merge) and R6 (single-kernel kNN, 128 blocks) both
// regressed: u64 keys double sort LDS traffic; 128-block kNN idles half the
// CUs. This 5-kernel split keeps every phase at >=256 blocks.

#define NB   4096
#define DIN  1024
#define NH1  128
#define NH2  64
#define SPLITK 4          // gemm1 K split: grid 128x4 = 512 blocks = 2/CU

// ---------------------------------------------------------------------------
// GEMM1 (split-K): part[s][n][m] = x[m][k in chunk s] @ W1[n][k]^T
// BM=32, BN=128, BK=16, 256 threads, thread tile 4x4.
// ---------------------------------------------------------------------------
__global__ __launch_bounds__(256) void gemm1_kernel(const float* __restrict__ A,
                                                    const float* __restrict__ Bw,
                                                    float* __restrict__ CP)
{
    const int K = DIN;
    const int M = NB;
    __shared__ float As[16 * 36];
    __shared__ float Bs[16 * 132];
    __shared__ float Cs[32 * 132];
    const int tid = threadIdx.x;
    const int m0  = blockIdx.x * 32;
    const int kb0 = blockIdx.y * (DIN / SPLITK);
    const int tr  = tid >> 5;
    const int tc  = tid & 31;
    const int am  = tid >> 4, ak = tid & 15;
    const int bn  = tid >> 2, bk = (tid & 3) << 2;

    float acc[4][4];
#pragma unroll
    for (int i = 0; i < 4; ++i)
#pragma unroll
        for (int j = 0; j < 4; ++j) acc[i][j] = 0.f;

    for (int k0 = 0; k0 < DIN / SPLITK; k0 += 16) {
        const int kb = kb0 + k0;
        As[ak * 36 + am]      = A[(size_t)(m0 + am) * K + kb + ak];
        As[ak * 36 + am + 16] = A[(size_t)(m0 + am + 16) * K + kb + ak];
        const float4 v0 = *(const float4*)&Bw[(size_t)bn * K + kb + bk];
        const float4 v1 = *(const float4*)&Bw[(size_t)(bn + 64) * K + kb + bk];
        Bs[(bk + 0) * 132 + bn] = v0.x;
        Bs[(bk + 1) * 132 + bn] = v0.y;
        Bs[(bk + 2) * 132 + bn] = v0.z;
        Bs[(bk + 3) * 132 + bn] = v0.w;
        Bs[(bk + 0) * 132 + bn + 64] = v1.x;
        Bs[(bk + 1) * 132 + bn + 64] = v1.y;
        Bs[(bk + 2) * 132 + bn + 64] = v1.z;
        Bs[(bk + 3) * 132 + bn + 64] = v1.w;
        __syncthreads();
#pragma unroll
        for (int k = 0; k < 16; ++k) {
            const float4 a = *(const float4*)&As[k * 36 + 4 * tr];
            const float4 b = *(const float4*)&Bs[k * 132 + 4 * tc];
            const float av[4] = {a.x, a.y, a.z, a.w};
#pragma unroll
            for (int mi = 0; mi < 4; ++mi) {
                acc[mi][0] = fmaf(av[mi], b.x, acc[mi][0]);
                acc[mi][1] = fmaf(av[mi], b.y, acc[mi][1]);
                acc[mi][2] = fmaf(av[mi], b.z, acc[mi][2]);
                acc[mi][3] = fmaf(av[mi], b.w, acc[mi][3]);
            }
        }
        __syncthreads();
    }

#pragma unroll
    for (int mi = 0; mi < 4; ++mi)
#pragma unroll
        for (int j = 0; j < 4; ++j)
            Cs[(4 * tr + mi) * 132 + 4 * tc + j] = acc[mi][j];
    __syncthreads();
#pragma unroll
    for (int it = 0; it < 16; ++it) {
        const int idx = it * 256 + tid;
        const int n = idx >> 5, m = idx & 31;
        CP[((size_t)blockIdx.y * NH1 + n) * M + m0 + m] = Cs[m * 132 + n];
    }
}

// ---------------------------------------------------------------------------
// Reduce split-K partials + bias + relu -> h1T[n][m].
// ---------------------------------------------------------------------------
__global__ __launch_bounds__(256) void reduce_relu_kernel(const float* __restrict__ P,
                                                          const float* __restrict__ bias,
                                                          float* __restrict__ h1T)
{
    const int i4 = (blockIdx.x * 256 + threadIdx.x) * 4;
    const int n  = i4 >> 12;
    const float4 a = *(const float4*)&P[i4];
    const float4 b = *(const float4*)&P[(size_t)NH1 * NB + i4];
    const float4 c = *(const float4*)&P[(size_t)2 * NH1 * NB + i4];
    const float4 d = *(const float4*)&P[(size_t)3 * NH1 * NB + i4];
    const float bv = bias[n];
    float4 o;
    o.x = fmaxf(a.x + b.x + c.x + d.x + bv, 0.f);
    o.y = fmaxf(a.y + b.y + c.y + d.y + bv, 0.f);
    o.z = fmaxf(a.z + b.z + c.z + d.z + bv, 0.f);
    o.w = fmaxf(a.w + b.w + c.w + d.w + bv, 0.f);
    *(float4*)&h1T[i4] = o;
}

// ---------------------------------------------------------------------------
// kNN stage 1: bitonic-sort each half-column (2048) — hybrid LDS/shuffle.
// All CE stages with j<=32 run in-register via __shfl_xor; only j>=64 stages
// touch LDS. grid 256 = 128 cols x 2 halves, 512 threads.
// ---------------------------------------------------------------------------
__global__ __launch_bounds__(512) void sort_half_kernel(const float* __restrict__ h1T,
                                                        float* __restrict__ sorted)
{
    __shared__ float s[2048];
    const int t = threadIdx.x;
    const int col  = blockIdx.x >> 1;
    const int half = blockIdx.x & 1;
    const float* __restrict__ src = h1T + (size_t)col * NB + half * 2048;

    float v[4];
#pragma unroll
    for (int q = 0; q < 4; ++q) v[q] = src[t + q * 512];

    // k = 2..64 entirely in registers (0 barriers)
#pragma unroll
    for (int k = 2; k <= 64; k <<= 1) {
#pragma unroll
        for (int j = k >> 1; j > 0; j >>= 1) {
#pragma unroll
            for (int q = 0; q < 4; ++q) {
                const int i = q * 512 + t;
                const float p = __shfl_xor(v[q], j);
                const bool up  = ((i & k) == 0);
                const bool low = ((i & j) == 0);
                v[q] = (low == up) ? fminf(v[q], p) : fmaxf(v[q], p);
            }
        }
    }
#pragma unroll
    for (int q = 0; q < 4; ++q) s[t + q * 512] = v[q];
    __syncthreads();

    for (int k = 128; k <= 2048; k <<= 1) {
        for (int j = k >> 1; j >= 64; j >>= 1) {
#pragma unroll
            for (int p = 0; p < 2; ++p) {
                const int c = t + p * 512;
                const int i = ((c & ~(j - 1)) << 1) | (c & (j - 1));
                const int ixj = i | j;
                const float a = s[i], b = s[ixj];
                const bool up = ((i & k) == 0);
                if ((a > b) == up) { s[i] = b; s[ixj] = a; }
            }
            __syncthreads();
        }
        // j = 32..1 in registers
#pragma unroll
        for (int q = 0; q < 4; ++q) v[q] = s[t + q * 512];
#pragma unroll
        for (int j = 32; j > 0; j >>= 1) {
#pragma unroll
            for (int q = 0; q < 4; ++q) {
                const int i = q * 512 + t;
                const float p = __shfl_xor(v[q], j);
                const bool up  = ((i & k) == 0);
                const bool low = ((i & j) == 0);
                v[q] = (low == up) ? fminf(v[q], p) : fmaxf(v[q], p);
            }
        }
#pragma unroll
        for (int q = 0; q < 4; ++q) s[t + q * 512] = v[q];
        __syncthreads();
    }

    float* __restrict__ dst = sorted + (size_t)col * NB + half * 2048;
#pragma unroll
    for (int q = 0; q < 4; ++q) dst[t + q * 512] = s[t + q * 512];
}

// ---------------------------------------------------------------------------
// kNN stage 2: 2 blocks per column (grid 256). Each block re-merges the two
// sorted halves via binary-search ranks (stable), then runs the 6-window
// phase on ITS half of the original elements (2/thread).
// ---------------------------------------------------------------------------
__global__ __launch_bounds__(1024) void knn_merge_kernel(const float* __restrict__ h1T,
                                                         const float* __restrict__ sorted,
                                                         float* __restrict__ prtT)
{
    __shared__ float sin_[NB];
    __shared__ float s[NB];
    const int col  = blockIdx.x >> 1;
    const int half = blockIdx.x & 1;
    const float* __restrict__ src = sorted + (size_t)col * NB;
#pragma unroll
    for (int p = 0; p < 4; ++p) sin_[threadIdx.x + p * 1024] = src[threadIdx.x + p * 1024];
    __syncthreads();

#pragma unroll
    for (int p = 0; p < 2; ++p) {
        const int j = threadIdx.x + p * 1024;   // 0..2047
        {   // half0 element: rank = j + #(half1 < v)
            const float v = sin_[j];
            int lo = 0, hi = 2048;
            while (lo < hi) { const int mid = (lo + hi) >> 1; if (sin_[2048 + mid] < v) lo = mid + 1; else hi = mid; }
            s[j + lo] = v;
        }
        {   // half1 element: rank = j + #(half0 <= v)
            const float v = sin_[2048 + j];
            int lo = 0, hi = 2048;
            while (lo < hi) { const int mid = (lo + hi) >> 1; if (sin_[mid] <= v) lo = mid + 1; else hi = mid; }
            s[j + lo] = v;
        }
    }
    __syncthreads();

    const float* __restrict__ colp = h1T + (size_t)col * NB;
#pragma unroll
    for (int p = 0; p < 2; ++p) {
        const int e   = half * 2048 + threadIdx.x + p * 1024;
        const float v = colp[e];
        int lo = 0, hi = NB;
        while (lo < hi) {
            const int mid = (lo + hi) >> 1;
            if (s[mid] < v) lo = mid + 1; else hi = mid;
        }
        int l = lo, h = lo;
        float sum = v;  // self
#pragma unroll
        for (int it = 0; it < 5; ++it) {
            const int li = (l > 0) ? l - 1 : 0;
            const int ri = (h < NB - 1) ? h + 1 : NB - 1;
            const float sl = s[li];
            const float sr = s[ri];
            const float dl = (l > 0) ? (v - sl) : 1e30f;
            const float dr = (h < NB - 1) ? (sr - v) : 1e30f;
            if (dl <= dr) { sum += sl; l = li; }
            else          { sum += sr; h = ri; }
        }
        prtT[(size_t)col * NB + e] = sum * (1.0f / 6.0f);
    }
}

// ---------------------------------------------------------------------------
// Fused tail: out = (relu(relu(prT^T @ Wpr^T + bpr) @ W2^T + b2)) @ Wo^T + bo
// Grid 256 blocks x 16 rows, 256 threads.
// ---------------------------------------------------------------------------
__global__ __launch_bounds__(256) void tail_kernel(const float* __restrict__ AT,
                                                   const float* __restrict__ Wpr,
                                                   const float* __restrict__ bpr,
                                                   const float* __restrict__ W2,
                                                   const float* __restrict__ b2,
                                                   const float* __restrict__ Wo,
                                                   const float* __restrict__ bo,
                                                   float* __restrict__ out)
{
    __shared__ float As[NH1 * 17];
    __shared__ float Bs[32 * 132];
    __shared__ float Ps[16 * 132];
    __shared__ float Rs[16 * 32];
    const int tid = threadIdx.x;
    const int m0  = blockIdx.x * 16;

    {
        const int row = tid >> 2;
        const int f   = (tid & 3) * 4;
#pragma unroll
        for (int h = 0; h < 2; ++h) {
            const int k = row + h * 64;
            const float4 v = *(const float4*)&AT[(size_t)k * NB + m0 + f];
            As[k * 17 + f + 0] = v.x;
            As[k * 17 + f + 1] = v.y;
            As[k * 17 + f + 2] = v.z;
            As[k * 17 + f + 3] = v.w;
        }
    }

    const int m  = tid & 15;
    const int g  = tid >> 4;     // 0..15
    const int n0 = g * 8;

    float acc[8];
#pragma unroll
    for (int j = 0; j < 8; ++j) acc[j] = 0.f;

    for (int k0 = 0; k0 < NH1; k0 += 32) {
        {
            const int n  = tid >> 1;
            const int ko = (tid & 1) * 16;
#pragma unroll
            for (int i4 = 0; i4 < 4; ++i4) {
                const float4 v = *(const float4*)&Wpr[(size_t)n * NH1 + k0 + ko + i4 * 4];
                Bs[(ko + i4 * 4 + 0) * 132 + n] = v.x;
                Bs[(ko + i4 * 4 + 1) * 132 + n] = v.y;
                Bs[(ko + i4 * 4 + 2) * 132 + n] = v.z;
                Bs[(ko + i4 * 4 + 3) * 132 + n] = v.w;
            }
        }
        __syncthreads();
#pragma unroll
        for (int kk = 0; kk < 32; ++kk) {
            const float a   = As[(k0 + kk) * 17 + m];
            const float4 b0 = *(const float4*)&Bs[kk * 132 + n0];
            const float4 b1 = *(const float4*)&Bs[kk * 132 + n0 + 4];
            acc[0] = fmaf(a, b0.x, acc[0]);
            acc[1] = fmaf(a, b0.y, acc[1]);
            acc[2] = fmaf(a, b0.z, acc[2]);
            acc[3] = fmaf(a, b0.w, acc[3]);
            acc[4] = fmaf(a, b1.x, acc[4]);
            acc[5] = fmaf(a, b1.y, acc[5]);
            acc[6] = fmaf(a, b1.z, acc[6]);
            acc[7] = fmaf(a, b1.w, acc[7]);
        }
        __syncthreads();
    }
#pragma unroll
    for (int j = 0; j < 8; ++j)
        Ps[m * 132 + n0 + j] = fmaxf(acc[j] + bpr[n0 + j], 0.f);
    __syncthreads();

    const int j0 = g * 4;
    float acc2[4] = {0.f, 0.f, 0.f, 0.f};
    for (int n0c = 0; n0c < NH1; n0c += 32) {
        {
            const int j2 = tid >> 2;
            const int no = (tid & 3) * 8;
#pragma unroll
            for (int i4 = 0; i4 < 2; ++i4) {
                const float4 v = *(const float4*)&W2[(size_t)j2 * NH1 + n0c + no + i4 * 4];
                Bs[(no + i4 * 4 + 0) * 68 + j2] = v.x;
                Bs[(no + i4 * 4 + 1) * 68 + j2] = v.y;
                Bs[(no + i4 * 4 + 2) * 68 + j2] = v.z;
                Bs[(no + i4 * 4 + 3) * 68 + j2] = v.w;
            }
        }
        __syncthreads();
#pragma unroll
        for (int nn = 0; nn < 32; ++nn) {
            const float p  = Ps[m * 132 + n0c + nn];
            const float4 w = *(const float4*)&Bs[nn * 68 + j0];
            acc2[0] = fmaf(p, w.x, acc2[0]);
            acc2[1] = fmaf(p, w.y, acc2[1]);
            acc2[2] = fmaf(p, w.z, acc2[2]);
            acc2[3] = fmaf(p, w.w, acc2[3]);
        }
        __syncthreads();
    }

    float po0 = 0.f, po1 = 0.f;
#pragma unroll
    for (int j = 0; j < 4; ++j) {
        const float h = fmaxf(acc2[j] + b2[j0 + j], 0.f);
        po0 = fmaf(h, Wo[j0 + j], po0);
        po1 = fmaf(h, Wo[NH2 + j0 + j], po1);
    }
    Rs[g * 32 + m * 2 + 0] = po0;
    Rs[g * 32 + m * 2 + 1] = po1;
    __syncthreads();
    if (tid < 32) {
        const int mm = tid >> 1, o = tid & 1;
        float sum = 0.f;
#pragma unroll
        for (int gg = 0; gg < 16; ++gg) sum += Rs[gg * 32 + mm * 2 + o];
        out[(size_t)(m0 + mm) * 2 + o] = sum + bo[o];
    }
}

extern "C" void kernel_launch(void* const* d_in, const int* in_sizes, int n_in,
                              void* d_out, int out_size, void* d_ws, size_t ws_size,
                              hipStream_t stream)
{
    const float* x   = (const float*)d_in[0];
    const float* W1  = (const float*)d_in[1];
    const float* b1  = (const float*)d_in[2];
    const float* Wpr = (const float*)d_in[3];
    const float* bpr = (const float*)d_in[4];
    const float* W2  = (const float*)d_in[5];
    const float* b2  = (const float*)d_in[6];
    const float* Wo  = (const float*)d_in[7];
    const float* bo  = (const float*)d_in[8];

    float* ws     = (float*)d_ws;
    float* part   = ws;                               // [4][128][4096]  8 MB
    float* h1T    = part + SPLITK * NH1 * NB;         // [128][4096]     2 MB
    float* sorted = h1T + NH1 * NB;                   // [128][4096]     2 MB
    float* prtT   = sorted + NH1 * NB;                // [128][4096]     2 MB

    gemm1_kernel<<<dim3(NB / 32, SPLITK), 256, 0, stream>>>(x, W1, part);
    reduce_relu_kernel<<<dim3(NH1 * NB / 4 / 256), 256, 0, stream>>>(part, b1, h1T);
    sort_half_kernel<<<dim3(NH1 * 2), 512, 0, stream>>>(h1T, sorted);
    knn_merge_kernel<<<dim3(NH1 * 2), 1024, 0, stream>>>(h1T, sorted, prtT);
    tail_kernel<<<dim3(NB / 16), 256, 0, stream>>>(prtT, Wpr, bpr, W2, b2, Wo, bo,
                                                   (float*)d_out);
}